// Round 1
// baseline (362.576 us; speedup 1.0000x reference)
//
#include <hip/hip_runtime.h>

#define PI_F 3.14159265358979323846f

template<int v> struct ic_t { static constexpr int value = v; };

template<int N, int I = 0, typename F>
__device__ __forceinline__ void sfor(F&& f) {
  if constexpr (I < N) { f(ic_t<I>{}); sfor<N, I + 1>(static_cast<F&&>(f)); }
}

__host__ __device__ constexpr int fold_idx(int t) {
  t &= 63;
  return (t <= 16) ? t : (t <= 32) ? (32 - t) : (t <= 48) ? (t - 32) : (64 - t);
}
__host__ __device__ constexpr float fold_sgn(int t) {
  t &= 63;
  return (t <= 16) ? 1.f : (t <= 48) ? -1.f : 1.f;
}

// cos/sin(2*pi*T/64) from register table cc[17]; T must be compile-time.
#define TCOS(T) (fold_sgn(T) * cc[fold_idx(T)])
#define TSIN(T) (fold_sgn(((T) + 48) & 63) * cc[fold_idx(((T) + 48) & 63)])

// ---------------------------------------------------------------------------
// Kernel 1: forward low-mode DFT. grid 2048 = {q,k} x (b*H+h)*E+e, block 256.
// Separable: 64->8 along n2 (radix-4 fold + literal twiddles), 32->8 along n1,
// 32->8 along n0. Output: 512 complex modes * (1/256), mode x = k0*64+k1*8+k2.
// ---------------------------------------------------------------------------
__global__ __launch_bounds__(256, 2)
void k1_fwd_dft(const float* __restrict__ qg, const float* __restrict__ kg,
                float2* __restrict__ qsel, float2* __restrict__ ksel)
{
  // A (half of n0): [k2][n0h<16][n1<32], n0h stride 36, k2 stride 577 -> 2-way max
  __shared__ float AhR[8 * 577];
  __shared__ float AhI[8 * 577];
  // Bv: [n0<32][k1<8][k2<8], n0 stride 68 -> 2-way max
  __shared__ float BrL[32 * 68];
  __shared__ float BiL[32 * 68];
  __shared__ float2 tw32s[32];

  const int tid = threadIdx.x;
  const int bid = blockIdx.x;
  const int t1023 = bid & 1023;
  const float* __restrict__ src = (bid < 1024 ? qg : kg) + (size_t)t1023 * 65536;
  float2* __restrict__ dst = (bid < 1024 ? qsel : ksel) + t1023 * 512;

  float cc[17];
  sfor<17>([&](auto J) { constexpr int j = decltype(J)::value;
    cc[j] = cosf((float)j * (PI_F / 32.f)); });

  if (tid < 32) {
    float s, c;
    sincosf((float)tid * (2.f * PI_F / 32.f), &s, &c);
    tw32s[tid] = make_float2(c, s);
  }

  for (int hf = 0; hf < 2; ++hf) {
    // ---- stage 1: rows [hf*512, hf*512+512), one row per thread x2
    for (int rr = 0; rr < 2; ++rr) {
      const int row = hf * 512 + rr * 256 + tid;
      const int n0h = (row >> 5) & 15;
      const int n1 = row & 31;
      const float4* __restrict__ rp = (const float4*)(src + (size_t)row * 64);
      float g0[16], g2[16], g1r[16], g1i[16];
      sfor<4>([&](auto JC) {
        constexpr int j = decltype(JC)::value;
        const float4 va = rp[j];
        const float4 vb = rp[4 + j];
        const float4 vc = rp[8 + j];
        const float4 vd = rp[12 + j];
        sfor<4>([&](auto MC) {
          constexpr int m = decltype(MC)::value;
          constexpr int r = 4 * j + m;
          const float xa = (m == 0) ? va.x : (m == 1) ? va.y : (m == 2) ? va.z : va.w;
          const float xb = (m == 0) ? vb.x : (m == 1) ? vb.y : (m == 2) ? vb.z : vb.w;
          const float xc = (m == 0) ? vc.x : (m == 1) ? vc.y : (m == 2) ? vc.z : vc.w;
          const float xd = (m == 0) ? vd.x : (m == 1) ? vd.y : (m == 2) ? vd.z : vd.w;
          const float s02 = xa + xc, d02 = xa - xc;
          const float s13 = xb + xd, d31 = xd - xb;
          g0[r] = s02 + s13; g2[r] = s02 - s13;
          g1r[r] = d02;      g1i[r] = d31;
        });
      });
      float Xr[8], Xi[8];
      sfor<8>([&](auto K) { Xr[decltype(K)::value] = 0.f; Xi[decltype(K)::value] = 0.f; });
      sfor<16>([&](auto RC) {
        constexpr int r = decltype(RC)::value;
        Xr[0] += g0[r];                        // k2=0: twiddle=1, imag exactly 0
        sfor<3>([&](auto EC) {
          constexpr int k2 = 2 * (decltype(EC)::value + 1);  // 2,4,6
          constexpr int t = (k2 * r) & 63;
          const float g = (k2 == 4) ? g0[r] : g2[r];
          Xr[k2] = fmaf(g,  TCOS(t), Xr[k2]);
          Xi[k2] = fmaf(-g, TSIN(t), Xi[k2]);
        });
        sfor<4>([&](auto UC) {
          constexpr int k2 = 2 * decltype(UC)::value + 1;    // 1,3,5,7
          constexpr int t = (k2 * r) & 63;
          const float gr = g1r[r];
          const float gi = ((k2 & 3) == 1) ? g1i[r] : -g1i[r];
          Xr[k2] = fmaf(gr, TCOS(t), fmaf(gi,  TSIN(t), Xr[k2]));
          Xi[k2] = fmaf(gi, TCOS(t), fmaf(-gr, TSIN(t), Xi[k2]));
        });
      });
      const int abase = n0h * 36 + n1;
      sfor<8>([&](auto K) {
        constexpr int k2 = decltype(K)::value;
        AhR[k2 * 577 + abase] = Xr[k2];
        AhI[k2 * 577 + abase] = Xi[k2];
      });
    }
    __syncthreads();
    // ---- stage 2: (n0h<16, k2<8) on tid<128; 8 k1 accumulators each
    if (tid < 128) {
      const int n0h = tid >> 3;
      const int k2 = tid & 7;
      const int n0 = hf * 16 + n0h;
      float br[8], bi[8];
      sfor<8>([&](auto K) { br[decltype(K)::value] = 0.f; bi[decltype(K)::value] = 0.f; });
      const int base = k2 * 577 + n0h * 36;
      sfor<32>([&](auto NC) {
        constexpr int n1 = decltype(NC)::value;
        const float ar = AhR[base + n1];
        const float ai = AhI[base + n1];
        sfor<8>([&](auto KC) {
          constexpr int k1 = decltype(KC)::value;
          constexpr int t = (2 * k1 * n1) & 63;
          br[k1] = fmaf(ar, TCOS(t), fmaf(ai,  TSIN(t), br[k1]));
          bi[k1] = fmaf(ai, TCOS(t), fmaf(-ar, TSIN(t), bi[k1]));
        });
      });
      sfor<8>([&](auto KC) {
        constexpr int k1 = decltype(KC)::value;
        BrL[n0 * 68 + k1 * 8 + k2] = br[k1];
        BiL[n0 * 68 + k1 * 8 + k2] = bi[k1];
      });
    }
    __syncthreads();
  }

  // ---- stage 3: lane=(k1,k2), wave -> k0 pair; wave-uniform tw32s broadcast
  {
    const int lane = tid & 63;
    const int wv = tid >> 6;
    const int k1 = lane >> 3;
    const int k2 = lane & 7;
    #pragma unroll
    for (int j = 0; j < 2; ++j) {
      const int k0 = wv * 2 + j;
      float xr = 0.f, xi = 0.f;
      #pragma unroll 8
      for (int n0 = 0; n0 < 32; ++n0) {
        const float br = BrL[n0 * 68 + k1 * 8 + k2];
        const float bi = BiL[n0 * 68 + k1 * 8 + k2];
        const float2 w = tw32s[(k0 * n0) & 31];
        xr = fmaf(br, w.x, fmaf(bi,  w.y, xr));
        xi = fmaf(bi, w.x, fmaf(-br, w.y, xi));
      }
      dst[(k0 << 6) + (k1 << 3) + k2] =
          make_float2(xr * (1.f / 256.f), xi * (1.f / 256.f));
    }
  }
}

// ---------------------------------------------------------------------------
// Kernel 2: fused complex attention  xqkv[e,x] = sum_y tanh(sum_e' Q K) * K.
// grid 256 = (b*H+h)*4 + xquarter; block 256 = 128 x-rows * 2 y-halves.
// K tile (64 KB) in LDS, broadcast reads; partial sums reduced through LDS.
// ---------------------------------------------------------------------------
__global__ __launch_bounds__(256, 2)
void k2_attn(const float2* __restrict__ qsel, const float2* __restrict__ ksel,
             float2* __restrict__ xqkv)
{
  __shared__ float2 Kl[8192];   // [e<16][y<512]
  const int tid = threadIdx.x;
  const int bh = blockIdx.x >> 2;
  const int xq = blockIdx.x & 3;

  const float2* __restrict__ kb = ksel + bh * 8192;
  for (int i = tid; i < 8192; i += 256) Kl[i] = kb[i];

  const int xr = tid & 127;
  const int yh = tid >> 7;
  const int x = xq * 128 + xr;
  const float2* __restrict__ qb = qsel + bh * 8192;
  float qr[16], qi[16], ar[16], ai[16];
  sfor<16>([&](auto E) {
    constexpr int e = decltype(E)::value;
    const float2 v = qb[e * 512 + x];
    qr[e] = v.x; qi[e] = v.y;
    ar[e] = 0.f; ai[e] = 0.f;
  });
  __syncthreads();

  const int y0 = yh * 256;
  for (int y = y0; y < y0 + 256; ++y) {
    float kr[16], ki[16];
    float sr = 0.f, si = 0.f;
    sfor<16>([&](auto E) {
      constexpr int e = decltype(E)::value;
      const float2 v = Kl[e * 512 + y];      // wave-uniform -> broadcast
      kr[e] = v.x; ki[e] = v.y;
      sr = fmaf(qr[e], v.x, fmaf(-qi[e], v.y, sr));
      si = fmaf(qr[e], v.y, fmaf( qi[e], v.x, si));
    });
    // complex tanh(sr + i si) = (sinh 2a + i sin 2b) / (cosh 2a + cos 2b)
    float a2 = 2.f * sr;
    a2 = fminf(fmaxf(a2, -30.f), 30.f);      // tanh saturated far before +/-30
    const float b2 = 2.f * si;
    const float ea = expf(a2);
    const float ei = 1.f / ea;
    const float sh = 0.5f * (ea - ei);
    const float chp = 0.5f * (ea + ei);
    float sb, cb;
    sincosf(b2, &sb, &cb);
    const float inv = 1.f / (chp + cb);
    const float tr = sh * inv;
    const float ti = sb * inv;
    sfor<16>([&](auto E) {
      constexpr int e = decltype(E)::value;
      ar[e] = fmaf(tr, kr[e], fmaf(-ti, ki[e], ar[e]));
      ai[e] = fmaf(tr, ki[e], fmaf( ti, kr[e], ai[e]));
    });
  }
  __syncthreads();
  float* __restrict__ red = (float*)Kl;      // K dead; reuse as reduction buf
  if (yh) {
    sfor<16>([&](auto E) {
      constexpr int e = decltype(E)::value;
      red[e * 128 + xr] = ar[e];
      red[2048 + e * 128 + xr] = ai[e];
    });
  }
  __syncthreads();
  if (!yh) {
    float2* __restrict__ ob = xqkv + bh * 8192;
    sfor<16>([&](auto E) {
      constexpr int e = decltype(E)::value;
      ob[e * 512 + x] = make_float2(ar[e] + red[e * 128 + xr],
                                    ai[e] + red[2048 + e * 128 + xr]);
    });
  }
}

// ---------------------------------------------------------------------------
// Kernel 3: w-multiply + analytic canonicalized inverse transform.
// out = (1/2^22) * sum_{k} w2(k2) cos(2pi k2 n2/64) * Re[F e^{i 2pi(k0n0+k1n1)/32}]
// grid 1024 = (b,h,o); block 256. Separable: A over k2, B over k1, C over k0.
// ---------------------------------------------------------------------------
#define SCALE_OUT (1.f / 4194304.f)

__global__ __launch_bounds__(256, 2)
void k3_inv(const float2* __restrict__ xqkv, const float* __restrict__ w_re,
            const float* __restrict__ w_im, float* __restrict__ out)
{
  __shared__ float2 Fs[512];
  __shared__ float cn[64];                   // cos(2*pi*t/64)
  __shared__ float Ur[4096], Ui[4096];       // [p=k0*8+k1][n2]
  __shared__ float Vr[2048], Vi[2048];       // [k0*4+n1loc][n2], 4-n1 chunks

  const int tid = threadIdx.x;
  const int bho = blockIdx.x;
  const int o = bho & 15;
  const int h = (bho >> 4) & 7;
  const int bh = bho >> 4;                   // b*8+h

  if (tid < 64) cn[tid] = cosf((float)tid * (PI_F / 32.f));

  float cc[17];
  sfor<17>([&](auto J) { constexpr int j = decltype(J)::value;
    cc[j] = cosf((float)j * (PI_F / 32.f)); });

  // F[x] = sum_e xqkv[e,x] * w[e,o,x], scaled
  const float2* __restrict__ xb = xqkv + bh * 8192;
  const float* __restrict__ wrb = w_re + ((size_t)(h * 256 + o)) * 512;
  const float* __restrict__ wib = w_im + ((size_t)(h * 256 + o)) * 512;
  for (int x = tid; x < 512; x += 256) {
    float fr = 0.f, fi = 0.f;
    sfor<16>([&](auto E) {
      constexpr int e = decltype(E)::value;
      const float2 v = xb[e * 512 + x];
      const float wr = wrb[e * 8192 + x];
      const float wi = wib[e * 8192 + x];
      fr = fmaf(v.x, wr, fmaf(-v.y, wi, fr));
      fi = fmaf(v.x, wi, fmaf( v.y, wr, fi));
    });
    Fs[x] = make_float2(fr * SCALE_OUT, fi * SCALE_OUT);
  }
  __syncthreads();

  const int n2 = tid & 63;
  const int wv = tid >> 6;

  // stage A: U[p][n2] = sum_k2 w2(k2) cos(2pi k2 n2/64) F[p*8+k2]
  #pragma unroll
  for (int i = 0; i < 16; ++i) {
    const int p = wv * 16 + i;
    float ur = 0.f, ui = 0.f;
    sfor<8>([&](auto KC) {
      constexpr int k2 = decltype(KC)::value;
      const float2 f = Fs[p * 8 + k2];       // wave-uniform broadcast
      const float cv = cn[(k2 * n2) & 63];
      const float wgt = (k2 == 0) ? cv : 2.f * cv;
      ur = fmaf(wgt, f.x, ur);
      ui = fmaf(wgt, f.y, ui);
    });
    Ur[p * 64 + n2] = ur;
    Ui[p * 64 + n2] = ui;
  }
  __syncthreads();

  // per-thread U registers for its two k0 columns
  float u_r[2][8], u_i[2][8];
  sfor<2>([&](auto JC) {
    constexpr int j = decltype(JC)::value;
    sfor<8>([&](auto KC) {
      constexpr int k1 = decltype(KC)::value;
      const int p = (wv * 2 + j) * 8 + k1;
      u_r[j][k1] = Ur[p * 64 + n2];
      u_i[j][k1] = Ui[p * 64 + n2];
    });
  });

  float* __restrict__ ob = out + (size_t)bho * 65536;

  for (int chq = 0; chq < 8; ++chq) {        // 4 n1 values per chunk
    // stage B: V[k0][n1loc][n2] = sum_k1 U * e^{+i 2pi k1 n1/32}
    sfor<2>([&](auto JC) {
      constexpr int j = decltype(JC)::value;
      const int k0 = wv * 2 + j;
      sfor<4>([&](auto LC) {
        constexpr int l = decltype(LC)::value;
        const int n1 = chq * 4 + l;
        float vr = 0.f, vi = 0.f;
        sfor<8>([&](auto KC) {
          constexpr int k1 = decltype(KC)::value;
          const int t = (2 * k1 * n1) & 63;  // wave-uniform -> broadcast reads
          const float cv = cn[t];
          const float sv = cn[(t + 48) & 63];
          vr = fmaf(u_r[j][k1], cv, fmaf(-u_i[j][k1], sv, vr));
          vi = fmaf(u_r[j][k1], sv, fmaf( u_i[j][k1], cv, vi));
        });
        Vr[(k0 * 4 + l) * 64 + n2] = vr;
        Vi[(k0 * 4 + l) * 64 + n2] = vi;
      });
    });
    __syncthreads();
    // stage C: out[n0][n1][n2] = sum_k0 Vr cos - Vi sin   (literal twiddles)
    {
      const int l = wv;
      float vrr[8], vii[8];
      sfor<8>([&](auto KC) {
        constexpr int k0 = decltype(KC)::value;
        vrr[k0] = Vr[(k0 * 4 + l) * 64 + n2];
        vii[k0] = Vi[(k0 * 4 + l) * 64 + n2];
      });
      const int n1 = chq * 4 + l;
      float* __restrict__ op = ob + n1 * 64 + n2;
      sfor<32>([&](auto NC) {
        constexpr int n0 = decltype(NC)::value;
        float acc = vrr[0];
        sfor<7>([&](auto KC) {
          constexpr int k0 = decltype(KC)::value + 1;
          constexpr int t = (2 * k0 * n0) & 63;
          acc = fmaf(vrr[k0], TCOS(t), fmaf(-vii[k0], TSIN(t), acc));
        });
        op[n0 * 2048] = acc;
      });
    }
    __syncthreads();
  }
}

// ---------------------------------------------------------------------------
extern "C" void kernel_launch(void* const* d_in, const int* in_sizes, int n_in,
                              void* d_out, int out_size, void* d_ws, size_t ws_size,
                              hipStream_t stream)
{
  (void)in_sizes; (void)n_in; (void)out_size; (void)ws_size;
  const float* q    = (const float*)d_in[0];
  const float* k    = (const float*)d_in[1];
  const float* w_re = (const float*)d_in[2];
  const float* w_im = (const float*)d_in[3];
  float* out = (float*)d_out;

  // workspace: qsel(4MB) | ksel(4MB) | xqkv(4MB), all [bh][e][x] float2
  float2* qsel = (float2*)d_ws;
  float2* ksel = qsel + 1024 * 512;
  float2* xqkv = ksel + 1024 * 512;

  hipLaunchKernelGGL(k1_fwd_dft, dim3(2048), dim3(256), 0, stream, q, k, qsel, ksel);
  hipLaunchKernelGGL(k2_attn,    dim3(256),  dim3(256), 0, stream, qsel, ksel, xqkv);
  hipLaunchKernelGGL(k3_inv,     dim3(1024), dim3(256), 0, stream, xqkv, w_re, w_im, out);
}